// Round 2
// baseline (844.608 us; speedup 1.0000x reference)
//
#include <hip/hip_runtime.h>

// Graph-attention sequential sweep as dataflow over the dependency DAG.
// Node i depends only on out-rows g[j] for j in neighbors[i], j<i, k<deg[i].
// Workers grab node ids IN ORDER via atomic counter (deadlock-free: the
// smallest unfinished id is always held by a resident wave whose deps are
// all finished, so it can always make progress).
//
// R1 change vs 842µs baseline: (a) gather loop batched 4 neighbors deep —
// 8 dwordx4 loads in flight per wave instead of 2 (VGPR was 28, VALUBusy 5%,
// pure load-latency bound); (b) grid 512 -> 1024 blocks (16 waves/CU).
//
// Coherence scheme (NO buffer_inv / NO buffer_wbl2 anywhere):
//  - producer: out-row stores write-through to LLC (sc0 sc1), ej_new + flag
//    via relaxed agent atomics (sc1), ordered by an explicit s_waitcnt.
//  - consumer: polls flags with relaxed agent loads (sc1, no L2 invalidate);
//    reads ej_new with relaxed agent loads; reads out-rows with NORMAL cached
//    loads — safe because each 2KB row occupies exclusive cachelines and is
//    first read only after its flag is set.

constexpr int NN = 50000;
constexpr int D  = 512;
constexpr int K  = 32;
constexpr int D4 = D / 4; // 128 float4 per row

typedef float v4f __attribute__((ext_vector_type(4)));

__device__ __forceinline__ void store_f4_llc(float* p, float4 v) {
    // write-through to the memory-side Infinity Cache (device coherence point)
    v4f vv; vv.x = v.x; vv.y = v.y; vv.z = v.z; vv.w = v.w;
    asm volatile("global_store_dwordx4 %0, %1, off sc0 sc1"
                 :: "v"(p), "v"(vv) : "memory");
}

__global__ __launch_bounds__(256) void precomp_kernel(
    const float* __restrict__ feats,
    const float* __restrict__ wq_w, const float* __restrict__ wq_b,
    const float* __restrict__ wk_w, const float* __restrict__ wk_b,
    float* __restrict__ ei, float* __restrict__ ej_orig)
{
    int gw   = (int)((blockIdx.x * blockDim.x + threadIdx.x) >> 6); // global wave id
    int lane = threadIdx.x & 63;
    if (gw >= NN) return;
    const float4* row = (const float4*)feats + (size_t)gw * D4;
    const float4* q4  = (const float4*)wq_w;
    const float4* k4  = (const float4*)wk_w;
    float dq = 0.f, dk = 0.f;
#pragma unroll
    for (int c = 0; c < 2; ++c) {
        float4 v  = row[lane + 64 * c];
        float4 q  = q4[lane + 64 * c];
        float4 kk = k4[lane + 64 * c];
        dq += v.x * q.x + v.y * q.y + v.z * q.z + v.w * q.w;
        dk += v.x * kk.x + v.y * kk.y + v.z * kk.z + v.w * kk.w;
    }
#pragma unroll
    for (int off = 32; off > 0; off >>= 1) {
        dq += __shfl_down(dq, off, 64);
        dk += __shfl_down(dk, off, 64);
    }
    if (lane == 0) {
        ei[gw]      = dq + wq_b[0];
        ej_orig[gw] = dk + wk_b[0];
    }
}

__global__ __launch_bounds__(256) void attn_dataflow(
    const float* __restrict__ feats,
    const int* __restrict__ neighbors, const int* __restrict__ deg,
    const float* __restrict__ ei_arr, const float* __restrict__ ej_orig,
    const float* __restrict__ wk_w, const float* __restrict__ wk_b,
    int* ej_new, int* flags, int* counter,
    float* out)
{
    const int lane = threadIdx.x & 63;
    const float4* f4  = (const float4*)feats;
    const float4* o4r = (const float4*)out;
    const float4* wk4 = (const float4*)wk_w;
    const float   wkb = wk_b[0];

    for (;;) {
        int id = 0;
        if (lane == 0) id = atomicAdd(counter, 1);
        id = __shfl(id, 0, 64);
        if (id >= NN) return;

        // ---- everything independent of deps, loaded BEFORE the wait ----
        const int d = deg[id];
        int nbr = 0;
        if (lane < K) nbr = neighbors[(size_t)id * K + lane];
        const bool valid = lane < d;                 // d <= 32, lanes>=32 never valid
        const bool isdep = valid && (nbr < id);

        const float4 c0 = f4[(size_t)id * D4 + lane];
        const float4 c1 = f4[(size_t)id * D4 + lane + 64];
        const float eii = ei_arr[id];
        float ej = 0.f;
        if (valid && !isdep) ej = ej_orig[nbr];

        // ---- wait for updated neighbors: relaxed sc1 polls, NO cache inv ----
        if (isdep) {
            while (__hip_atomic_load(&flags[nbr], __ATOMIC_RELAXED,
                                     __HIP_MEMORY_SCOPE_AGENT) == 0) {
                __builtin_amdgcn_s_sleep(1);
            }
            ej = __int_as_float(__hip_atomic_load(&ej_new[nbr], __ATOMIC_RELAXED,
                                                  __HIP_MEMORY_SCOPE_AGENT));
        }

        float4 acc0 = {0.f, 0.f, 0.f, 0.f};
        float4 acc1 = {0.f, 0.f, 0.f, 0.f};

        if (d > 0) {
            float eij = valid ? eii * ej : -3.0e38f;
            float m = eij;
#pragma unroll
            for (int off = 32; off > 0; off >>= 1)
                m = fmaxf(m, __shfl_xor(m, off, 64));
            float p = valid ? __expf(eij - m) : 0.f;
            float s = p;
#pragma unroll
            for (int off = 32; off > 0; off >>= 1)
                s += __shfl_xor(s, off, 64);
            const float inv_s = 1.0f / s;

            // ---- batch-4 gather: 8 dwordx4 loads in flight per iteration ----
            for (int k = 0; k < d; k += 4) {
                float aw[4];
                const float4* srcp[4];
#pragma unroll
                for (int t = 0; t < 4; ++t) {
                    int kk = k + t;
                    int kc = (kk < d) ? kk : (d - 1);   // wave-uniform clamp
                    float a = __shfl(p, kc, 64) * inv_s;
                    aw[t] = (kk < d) ? a : 0.f;          // dup loads get weight 0
                    int j  = __shfl(nbr, kc, 64);
                    srcp[t] = (j < id) ? (o4r + (size_t)j * D4)
                                       : (f4  + (size_t)j * D4);
                }
                float4 v0[4], v1[4];
#pragma unroll
                for (int t = 0; t < 4; ++t) {
                    v0[t] = srcp[t][lane];
                    v1[t] = srcp[t][lane + 64];
                }
#pragma unroll
                for (int t = 0; t < 4; ++t) {
                    acc0.x += aw[t] * v0[t].x; acc0.y += aw[t] * v0[t].y;
                    acc0.z += aw[t] * v0[t].z; acc0.w += aw[t] * v0[t].w;
                    acc1.x += aw[t] * v1[t].x; acc1.y += aw[t] * v1[t].y;
                    acc1.z += aw[t] * v1[t].z; acc1.w += aw[t] * v1[t].w;
                }
            }
        }

        float4 g0 = {c0.x + acc0.x, c0.y + acc0.y, c0.z + acc0.z, c0.w + acc0.w};
        float4 g1 = {c1.x + acc1.x, c1.y + acc1.y, c1.z + acc1.z, c1.w + acc1.w};
        float* orow = out + (size_t)id * D;
        store_f4_llc(orow + 4 * lane,        g0);
        store_f4_llc(orow + 4 * (lane + 64), g1);

        // ej_new[id] = g . wk + bk
        float4 w0 = wk4[lane], w1 = wk4[lane + 64];
        float pd = g0.x * w0.x + g0.y * w0.y + g0.z * w0.z + g0.w * w0.w
                 + g1.x * w1.x + g1.y * w1.y + g1.z * w1.z + g1.w * w1.w;
#pragma unroll
        for (int off = 32; off > 0; off >>= 1)
            pd += __shfl_xor(pd, off, 64);
        if (lane == 0)
            __hip_atomic_store(&ej_new[id], __float_as_int(pd + wkb),
                               __ATOMIC_RELAXED, __HIP_MEMORY_SCOPE_AGENT);

        // order payload (row + ej_new, all at LLC) before the flag; no wbl2
        __builtin_amdgcn_s_waitcnt(0);
        if (lane == 0)
            __hip_atomic_store(&flags[id], 1, __ATOMIC_RELAXED,
                               __HIP_MEMORY_SCOPE_AGENT);
    }
}

extern "C" void kernel_launch(void* const* d_in, const int* in_sizes, int n_in,
                              void* d_out, int out_size, void* d_ws, size_t ws_size,
                              hipStream_t stream)
{
    const float* feats     = (const float*)d_in[0];
    const float* wq_w      = (const float*)d_in[1];
    const float* wq_b      = (const float*)d_in[2];
    const float* wk_w      = (const float*)d_in[3];
    const float* wk_b      = (const float*)d_in[4];
    const int*   neighbors = (const int*)d_in[5];
    const int*   deg       = (const int*)d_in[6];
    float*       out       = (float*)d_out;

    // ws: [flags: NN][pad][counter][pad][ei: NN f][ej_orig: NN f][ej_new: NN i]
    char*  ws      = (char*)d_ws;
    int*   flags   = (int*)ws;
    int*   counter = flags + NN + 64;               // own cacheline
    float* ei      = (float*)(ws + (size_t)(NN + 128) * sizeof(int));
    float* ej_orig = ei + NN;
    int*   ej_new  = (int*)(ej_orig + NN);

    (void)hipMemsetAsync(d_ws, 0, (size_t)(NN + 128) * sizeof(int), stream);

    dim3 pb(256), pg((NN + 3) / 4);
    precomp_kernel<<<pg, pb, 0, stream>>>(feats, wq_w, wq_b, wk_w, wk_b, ei, ej_orig);

    // 1024 blocks = 16 waves/CU co-resident (VGPR should stay <= ~96).
    attn_dataflow<<<dim3(1024), dim3(256), 0, stream>>>(
        feats, neighbors, deg, ei, ej_orig, wk_w, wk_b, ej_new, flags, counter, out);
}

// Round 3
// 826.065 us; speedup vs baseline: 1.0224x; 1.0224x over previous
//
#include <hip/hip_runtime.h>

// Graph-attention sequential sweep as dataflow over the dependency DAG.
// Node i depends only on out-rows g[j] for j in neighbors[i], j<i, k<deg[i].
// Workers grab node ids IN ORDER via atomic counter (deadlock-free: the
// smallest unfinished id is always held by a resident wave whose deps are
// all finished, so it can always make progress).
//
// R3: kernel is DEPENDENCY-CHAIN bound (R2: 2x occupancy + 4x MLP => zero
// change, VALUBusy 5%). Chain depth ~178 steps. This version minimizes the
// serial work per chain step:
//  (a) eager online-softmax: neighbors are accumulated the moment they are
//      ready (non-deps immediately, deps in publish order) with running-max
//      rescaling, so after the LAST dep publishes only ONE row remains.
//  (b) ej_new doubles as the ready flag (sentinel: bits==0 means not ready;
//      +0.0 results are nudged to a denormal). Removes one serial LLC
//      round-trip (flag load -> ej load) per chain step.
//
// Coherence scheme (NO buffer_inv / NO buffer_wbl2 anywhere):
//  - producer: out-row stores write-through to LLC (sc0 sc1); ej_new (the
//    combined payload+flag) via relaxed agent atomic, ordered after the row
//    stores by an explicit s_waitcnt(0).
//  - consumer: polls ej_new with relaxed agent loads (sc1, no L2 inv);
//    reads out-rows with NORMAL cached loads — safe because each 2KB row
//    occupies exclusive cachelines and is first read only after its ej_new
//    is seen nonzero, so no stale copy can exist in any cache.

constexpr int NN = 50000;
constexpr int D  = 512;
constexpr int K  = 32;
constexpr int D4 = D / 4; // 128 float4 per row

typedef float v4f __attribute__((ext_vector_type(4)));

__device__ __forceinline__ void store_f4_llc(float* p, float4 v) {
    // write-through to the memory-side Infinity Cache (device coherence point)
    v4f vv; vv.x = v.x; vv.y = v.y; vv.z = v.z; vv.w = v.w;
    asm volatile("global_store_dwordx4 %0, %1, off sc0 sc1"
                 :: "v"(p), "v"(vv) : "memory");
}

__global__ __launch_bounds__(256) void precomp_kernel(
    const float* __restrict__ feats,
    const float* __restrict__ wq_w, const float* __restrict__ wq_b,
    const float* __restrict__ wk_w, const float* __restrict__ wk_b,
    float* __restrict__ ei, float* __restrict__ ej_orig)
{
    int gw   = (int)((blockIdx.x * blockDim.x + threadIdx.x) >> 6); // global wave id
    int lane = threadIdx.x & 63;
    if (gw >= NN) return;
    const float4* row = (const float4*)feats + (size_t)gw * D4;
    const float4* q4  = (const float4*)wq_w;
    const float4* k4  = (const float4*)wk_w;
    float dq = 0.f, dk = 0.f;
#pragma unroll
    for (int c = 0; c < 2; ++c) {
        float4 v  = row[lane + 64 * c];
        float4 q  = q4[lane + 64 * c];
        float4 kk = k4[lane + 64 * c];
        dq += v.x * q.x + v.y * q.y + v.z * q.z + v.w * q.w;
        dk += v.x * kk.x + v.y * kk.y + v.z * kk.z + v.w * kk.w;
    }
#pragma unroll
    for (int off = 32; off > 0; off >>= 1) {
        dq += __shfl_down(dq, off, 64);
        dk += __shfl_down(dk, off, 64);
    }
    if (lane == 0) {
        ei[gw]      = dq + wq_b[0];
        ej_orig[gw] = dk + wk_b[0];
    }
}

__global__ __launch_bounds__(256) void attn_dataflow(
    const float* __restrict__ feats,
    const int* __restrict__ neighbors, const int* __restrict__ deg,
    const float* __restrict__ ei_arr, const float* __restrict__ ej_orig,
    const float* __restrict__ wk_w, const float* __restrict__ wk_b,
    int* ej_new, int* counter,
    float* out)
{
    const int lane = threadIdx.x & 63;
    const float4* f4  = (const float4*)feats;
    const float4* o4r = (const float4*)out;
    const float4* wk4 = (const float4*)wk_w;
    const float   wkb = wk_b[0];

    for (;;) {
        int id = 0;
        if (lane == 0) id = atomicAdd(counter, 1);
        id = __shfl(id, 0, 64);
        if (id >= NN) return;

        const int d = deg[id];
        int nbr = 0;
        if (lane < K) nbr = neighbors[(size_t)id * K + lane];
        const bool valid = lane < d;                 // d <= 32, lanes>=32 never valid
        const bool isdep = valid && (nbr < id);

        const float4 c0 = f4[(size_t)id * D4 + lane];
        const float4 c1 = f4[(size_t)id * D4 + lane + 64];
        const float eii = ei_arr[id];

        // eij known immediately for non-dep neighbors
        float eij = 0.f;
        if (valid && !isdep) eij = eii * ej_orig[nbr];

        // ---- eager online-softmax accumulation over ready neighbors ----
        float4 acc0 = {0.f, 0.f, 0.f, 0.f};
        float4 acc1 = {0.f, 0.f, 0.f, 0.f};
        float m = -3.0e38f, s = 0.f;

        unsigned long long pend = __ballot(valid && !isdep); // ready, unprocessed
        unsigned long long wait = __ballot(isdep);           // deps not yet ready

        while (pend | wait) {
            if (!pend) {
                // poll ALL remaining deps in parallel (one lane each)
                int pv = 0;
                const bool w = (wait >> lane) & 1ULL;
                if (w) pv = __hip_atomic_load(&ej_new[nbr], __ATOMIC_RELAXED,
                                              __HIP_MEMORY_SCOPE_AGENT);
                unsigned long long ready = __ballot(w && pv != 0);
                if (!ready) { __builtin_amdgcn_s_sleep(1); continue; }
                if (w && pv != 0) eij = eii * __int_as_float(pv);
                pend = ready;
                wait &= ~ready;
            }
            // take up to 4 ready neighbors (wave-uniform extraction)
            int cnt = 0;
            int   js[4]; float ee[4];
#pragma unroll
            for (int t = 0; t < 4; ++t) {
                if (pend) {
                    int k = (int)__ffsll(pend) - 1;
                    pend &= pend - 1;
                    ee[cnt] = __shfl(eij, k, 64);
                    js[cnt] = __shfl(nbr, k, 64);
                    ++cnt;
                }
            }
            // issue row loads FIRST so exp/rescale overlaps their flight
            float4 v0[4], v1[4];
#pragma unroll
            for (int t = 0; t < 4; ++t) {
                if (t < cnt) {
                    const float4* sp = (js[t] < id) ? (o4r + (size_t)js[t] * D4)
                                                    : (f4  + (size_t)js[t] * D4);
                    v0[t] = sp[lane];
                    v1[t] = sp[lane + 64];
                }
            }
            float mb = m;
#pragma unroll
            for (int t = 0; t < 4; ++t) if (t < cnt) mb = fmaxf(mb, ee[t]);
            if (mb > m) {
                const float r = __expf(m - mb);   // first time: exp(-inf)=0
                acc0.x *= r; acc0.y *= r; acc0.z *= r; acc0.w *= r;
                acc1.x *= r; acc1.y *= r; acc1.z *= r; acc1.w *= r;
                s *= r; m = mb;
            }
#pragma unroll
            for (int t = 0; t < 4; ++t) {
                if (t < cnt) {
                    const float wt = __expf(ee[t] - m);
                    s += wt;
                    acc0.x += wt * v0[t].x; acc0.y += wt * v0[t].y;
                    acc0.z += wt * v0[t].z; acc0.w += wt * v0[t].w;
                    acc1.x += wt * v1[t].x; acc1.y += wt * v1[t].y;
                    acc1.z += wt * v1[t].z; acc1.w += wt * v1[t].w;
                }
            }
        }

        const float inv_s = (s > 0.f) ? (1.0f / s) : 0.f;  // d==0 -> acc==0
        float4 g0 = {c0.x + acc0.x * inv_s, c0.y + acc0.y * inv_s,
                     c0.z + acc0.z * inv_s, c0.w + acc0.w * inv_s};
        float4 g1 = {c1.x + acc1.x * inv_s, c1.y + acc1.y * inv_s,
                     c1.z + acc1.z * inv_s, c1.w + acc1.w * inv_s};
        float* orow = out + (size_t)id * D;
        store_f4_llc(orow + 4 * lane,        g0);
        store_f4_llc(orow + 4 * (lane + 64), g1);

        // ej_new[id] = g . wk + bk  (computed while row stores are in flight)
        float4 w0 = wk4[lane], w1 = wk4[lane + 64];
        float pd = g0.x * w0.x + g0.y * w0.y + g0.z * w0.z + g0.w * w0.w
                 + g1.x * w1.x + g1.y * w1.y + g1.z * w1.z + g1.w * w1.w;
#pragma unroll
        for (int off = 32; off > 0; off >>= 1)
            pd += __shfl_xor(pd, off, 64);

        int bits = __float_as_int(pd + wkb);
        if (bits == 0) bits = 1;   // avoid the not-ready sentinel (+0.0 -> 1e-45)

        // order the row payload (at LLC) before the combined flag+payload
        __builtin_amdgcn_s_waitcnt(0);
        if (lane == 0)
            __hip_atomic_store(&ej_new[id], bits,
                               __ATOMIC_RELAXED, __HIP_MEMORY_SCOPE_AGENT);
    }
}

extern "C" void kernel_launch(void* const* d_in, const int* in_sizes, int n_in,
                              void* d_out, int out_size, void* d_ws, size_t ws_size,
                              hipStream_t stream)
{
    const float* feats     = (const float*)d_in[0];
    const float* wq_w      = (const float*)d_in[1];
    const float* wq_b      = (const float*)d_in[2];
    const float* wk_w      = (const float*)d_in[3];
    const float* wk_b      = (const float*)d_in[4];
    const int*   neighbors = (const int*)d_in[5];
    const int*   deg       = (const int*)d_in[6];
    float*       out       = (float*)d_out;

    // ws: [ej_new: NN i (doubles as ready flag)][pad][counter][pad][ei: NN f][ej_orig: NN f]
    char*  ws      = (char*)d_ws;
    int*   ej_new  = (int*)ws;
    int*   counter = ej_new + NN + 64;              // own cacheline
    float* ei      = (float*)(ws + (size_t)(NN + 128) * sizeof(int));
    float* ej_orig = ei + NN;

    (void)hipMemsetAsync(d_ws, 0, (size_t)(NN + 128) * sizeof(int), stream);

    dim3 pb(256), pg((NN + 3) / 4);
    precomp_kernel<<<pg, pb, 0, stream>>>(feats, wq_w, wq_b, wk_w, wk_b, ei, ej_orig);

    attn_dataflow<<<dim3(1024), dim3(256), 0, stream>>>(
        feats, neighbors, deg, ei, ej_orig, wk_w, wk_b, ej_new, counter, out);
}